// Round 1
// baseline (139.144 us; speedup 1.0000x reference)
//
#include <hip/hip_runtime.h>
#include <math.h>

// Problem constants (match reference)
#define BB 65536
#define KK 10
#define EE 128
#define VV 100000

constexpr int BLOCK = 256;              // 4 waves
constexpr int GRID  = 2048;             // 8192 waves total = full machine
constexpr int WAVES = GRID * (BLOCK / 64);

__device__ __forceinline__ float softplus_f(float x) {
    // softplus(x) = max(x,0) + log1p(exp(-|x|))  (numerically stable)
    float ax = fabsf(x);
    return fmaxf(x, 0.0f) + log1pf(__expf(-ax));
}

__global__ __launch_bounds__(BLOCK) void
w2v_loss_kernel(const int* __restrict__ cw,
                const int* __restrict__ ow,
                const int* __restrict__ neg,
                const float* __restrict__ emb,
                float* __restrict__ partial) {
    const int lane = threadIdx.x & 63;
    const int wv   = threadIdx.x >> 6;
    const int gw   = blockIdx.x * (BLOCK / 64) + wv;   // global wave id

    float acc = 0.0f;

    for (int b = gw; b < BB; b += WAVES) {
        const int c = cw[b];
        const float2 ec = ((const float2*)(emb + (size_t)c * EE))[lane];
        const int o = ow[b];
        const float2 eo = ((const float2*)(emb + (size_t)o * EE))[lane];

        float pd = ec.x * eo.x + ec.y * eo.y;

        float nd[KK];
        #pragma unroll
        for (int k = 0; k < KK; ++k) {
            const int n = neg[b * KK + k];
            const float2 en = ((const float2*)(emb + (size_t)n * EE))[lane];
            nd[k] = ec.x * en.x + ec.y * en.y;
        }

        // Butterfly reduce all 11 dot partials across the 64-lane wave.
        #pragma unroll
        for (int s = 1; s < 64; s <<= 1) {
            pd += __shfl_xor(pd, s);
            #pragma unroll
            for (int k = 0; k < KK; ++k) nd[k] += __shfl_xor(nd[k], s);
        }

        // All lanes now hold the full dots; lane 0 accumulates the loss.
        if (lane == 0) {
            float loss = softplus_f(-pd);          // -log_sigmoid(pos_dot)
            #pragma unroll
            for (int k = 0; k < KK; ++k)
                loss += softplus_f(nd[k]);          // -log_sigmoid(-dot) = softplus(dot)
            acc += loss;
        }
    }

    __shared__ float smem[BLOCK / 64];
    if (lane == 0) smem[wv] = acc;
    __syncthreads();
    if (threadIdx.x == 0) {
        float s = 0.0f;
        #pragma unroll
        for (int w = 0; w < BLOCK / 64; ++w) s += smem[w];
        partial[blockIdx.x] = s;
    }
}

__global__ __launch_bounds__(256) void
w2v_reduce_kernel(const float* __restrict__ partial, float* __restrict__ out) {
    // Single block, deterministic tree reduction of GRID partials.
    __shared__ float smem[256];
    float s = 0.0f;
    for (int i = threadIdx.x; i < GRID; i += 256) s += partial[i];
    smem[threadIdx.x] = s;
    __syncthreads();
    for (int step = 128; step > 0; step >>= 1) {
        if (threadIdx.x < step) smem[threadIdx.x] += smem[threadIdx.x + step];
        __syncthreads();
    }
    if (threadIdx.x == 0) out[0] = smem[0] / (float)BB;
}

extern "C" void kernel_launch(void* const* d_in, const int* in_sizes, int n_in,
                              void* d_out, int out_size, void* d_ws, size_t ws_size,
                              hipStream_t stream) {
    const int*   cw  = (const int*)d_in[0];
    const int*   ow  = (const int*)d_in[1];
    const int*   neg = (const int*)d_in[2];
    const float* emb = (const float*)d_in[3];
    float* out = (float*)d_out;
    float* partial = (float*)d_ws;   // GRID floats of scratch

    w2v_loss_kernel<<<GRID, BLOCK, 0, stream>>>(cw, ow, neg, emb, partial);
    w2v_reduce_kernel<<<1, 256, 0, stream>>>(partial, out);
}

// Round 2
// 85.753 us; speedup vs baseline: 1.6226x; 1.6226x over previous
//
#include <hip/hip_runtime.h>
#include <math.h>

// Problem constants (match reference)
#define BB 65536
#define KK 10
#define EE 128

constexpr int BLOCK = 256;          // 4 waves
constexpr int BPB   = 16;           // b's per block: 4 waves x 4 groups of 16 lanes
constexpr int GRID  = BB / BPB;     // 4096 blocks, one pass, no grid-stride

__device__ __forceinline__ float softplus_f(float x) {
    // softplus(x) = max(x,0) + log(1+exp(-|x|)), fast intrinsics (tolerance is huge)
    float ax = fabsf(x);
    return fmaxf(x, 0.0f) + __logf(1.0f + __expf(-ax));
}

__device__ __forceinline__ float dot8(const float4& a0, const float4& a1,
                                      const float4& b0, const float4& b1) {
    float s = a0.x * b0.x;
    s = fmaf(a0.y, b0.y, s);
    s = fmaf(a0.z, b0.z, s);
    s = fmaf(a0.w, b0.w, s);
    s = fmaf(a1.x, b1.x, s);
    s = fmaf(a1.y, b1.y, s);
    s = fmaf(a1.z, b1.z, s);
    s = fmaf(a1.w, b1.w, s);
    return s;
}

__global__ __launch_bounds__(BLOCK) void
w2v_loss_kernel(const int* __restrict__ cw,
                const int* __restrict__ ow,
                const int* __restrict__ neg,
                const float* __restrict__ emb,
                float* __restrict__ partial) {
    const int tid = threadIdx.x;
    const int li  = tid & 15;              // lane-in-group (16-lane groups)
    const int grp = tid >> 4;              // group index in block, 0..15
    const int b   = blockIdx.x * BPB + grp;

    // Per-group indices (each 16-lane group loads the same address -> 1 value
    // replicated; 4 distinct addresses per wave per load instruction).
    const int c = cw[b];
    const int o = ow[b];

    const float4* ebase = (const float4*)emb;      // row r = 32 float4's
    const size_t f4 = (size_t)li * 2;              // this lane's 32B slice

    const float4 ec0 = ebase[(size_t)c * 32 + f4];
    const float4 ec1 = ebase[(size_t)c * 32 + f4 + 1];
    const float4 eo0 = ebase[(size_t)o * 32 + f4];
    const float4 eo1 = ebase[(size_t)o * 32 + f4 + 1];

    float pd = dot8(ec0, ec1, eo0, eo1);

    float nd[KK];
    #pragma unroll
    for (int k = 0; k < KK; ++k) {
        const int n = neg[b * KK + k];
        const float4 en0 = ebase[(size_t)n * 32 + f4];
        const float4 en1 = ebase[(size_t)n * 32 + f4 + 1];
        nd[k] = dot8(ec0, ec1, en0, en1);
    }

    // Reduce across the 16-lane group only: masks 1,2,4,8 (single ds_swizzle each).
    #pragma unroll
    for (int s = 1; s < 16; s <<= 1) {
        pd += __shfl_xor(pd, s);
        #pragma unroll
        for (int k = 0; k < KK; ++k) nd[k] += __shfl_xor(nd[k], s);
    }

    // Every lane in the group now holds the full dots; compute loss (all 4
    // groups of a wave run their softplus chain in parallel).
    float loss = softplus_f(-pd);              // -log_sigmoid(pos_dot)
    #pragma unroll
    for (int k = 0; k < KK; ++k)
        loss += softplus_f(nd[k]);             // -log_sigmoid(-dot) = softplus(dot)

    __shared__ float smem[BPB];
    if (li == 0) smem[grp] = loss;
    __syncthreads();
    if (tid == 0) {
        float s = 0.0f;
        #pragma unroll
        for (int g = 0; g < BPB; ++g) s += smem[g];
        partial[blockIdx.x] = s;
    }
}

__global__ __launch_bounds__(256) void
w2v_reduce_kernel(const float* __restrict__ partial, float* __restrict__ out) {
    // Single block, deterministic tree reduction of GRID partials.
    __shared__ float smem[256];
    float s = 0.0f;
    for (int i = threadIdx.x; i < GRID; i += 256) s += partial[i];
    smem[threadIdx.x] = s;
    __syncthreads();
    for (int step = 128; step > 0; step >>= 1) {
        if (threadIdx.x < step) smem[threadIdx.x] += smem[threadIdx.x + step];
        __syncthreads();
    }
    if (threadIdx.x == 0) out[0] = smem[0] / (float)BB;
}

extern "C" void kernel_launch(void* const* d_in, const int* in_sizes, int n_in,
                              void* d_out, int out_size, void* d_ws, size_t ws_size,
                              hipStream_t stream) {
    const int*   cw  = (const int*)d_in[0];
    const int*   ow  = (const int*)d_in[1];
    const int*   neg = (const int*)d_in[2];
    const float* emb = (const float*)d_in[3];
    float* out = (float*)d_out;
    float* partial = (float*)d_ws;   // GRID floats of scratch

    w2v_loss_kernel<<<GRID, BLOCK, 0, stream>>>(cw, ow, neg, emb, partial);
    w2v_reduce_kernel<<<1, 256, 0, stream>>>(partial, out);
}

// Round 3
// 49.275 us; speedup vs baseline: 2.8238x; 1.7403x over previous
//
#include <hip/hip_runtime.h>
#include <math.h>
#include <stdint.h>

// Problem constants (match reference)
#define BB 65536
#define KK 10
#define EE 128
#define VV 100000

constexpr int BLOCK = 256;          // 4 waves
constexpr int BPB   = 16;           // b's per block: 16 groups of 16 lanes
constexpr int GRID  = BB / BPB;     // 4096 blocks

constexpr size_t PARTIAL_BYTES = (size_t)GRID * sizeof(float);
constexpr size_t TBL_OFF       = 32768;                     // bf16 table offset in ws (aligned)
constexpr size_t TBL_BYTES     = (size_t)VV * EE * 2;       // 25.6 MB

__device__ __forceinline__ float softplus_f(float x) {
    float ax = fabsf(x);
    return fmaxf(x, 0.0f) + __logf(1.0f + __expf(-ax));
}

// ---- fp32 -> bf16 (RNE) table conversion --------------------------------
__global__ __launch_bounds__(256) void
convert_kernel(const float* __restrict__ emb, uint32_t* __restrict__ tbl) {
    // Each thread converts 8 floats -> 4 packed u32 (8 bf16) per iter.
    const int nq = VV * EE / 8;                 // 1.6M chunks of 8
    const int stride = gridDim.x * blockDim.x;
    for (int q = blockIdx.x * blockDim.x + threadIdx.x; q < nq; q += stride) {
        const float4 a = ((const float4*)emb)[q * 2];
        const float4 b = ((const float4*)emb)[q * 2 + 1];
        float v[8] = {a.x, a.y, a.z, a.w, b.x, b.y, b.z, b.w};
        uint32_t p[4];
        #pragma unroll
        for (int i = 0; i < 4; ++i) {
            uint32_t lo = __float_as_uint(v[2 * i]);
            uint32_t hi = __float_as_uint(v[2 * i + 1]);
            lo = (lo + 0x7FFFu + ((lo >> 16) & 1u)) >> 16;   // RNE
            hi = (hi + 0x7FFFu + ((hi >> 16) & 1u)) & 0xFFFF0000u;
            p[i] = lo | hi;
        }
        ((uint4*)tbl)[q] = make_uint4(p[0], p[1], p[2], p[3]);
    }
}

// ---- bf16 gather + loss --------------------------------------------------
__device__ __forceinline__ float dot_bf16x8(const uint4& cu, const uint4& xu) {
    // Each u32 holds 2 bf16; f32 = bits<<16 (low) / bits&0xFFFF0000 (high).
    const uint32_t ca[4] = {cu.x, cu.y, cu.z, cu.w};
    const uint32_t xa[4] = {xu.x, xu.y, xu.z, xu.w};
    float s = 0.0f;
    #pragma unroll
    for (int i = 0; i < 4; ++i) {
        float c0 = __uint_as_float(ca[i] << 16);
        float c1 = __uint_as_float(ca[i] & 0xFFFF0000u);
        float x0 = __uint_as_float(xa[i] << 16);
        float x1 = __uint_as_float(xa[i] & 0xFFFF0000u);
        s = fmaf(c0, x0, s);
        s = fmaf(c1, x1, s);
    }
    return s;
}

__global__ __launch_bounds__(BLOCK) void
w2v_loss_bf16_kernel(const int* __restrict__ cw,
                     const int* __restrict__ ow,
                     const int* __restrict__ neg,
                     const uint32_t* __restrict__ tbl,
                     float* __restrict__ partial) {
    const int tid = threadIdx.x;
    const int li  = tid & 15;
    const int grp = tid >> 4;
    const int b   = blockIdx.x * BPB + grp;

    const int c = cw[b];
    const int o = ow[b];

    const uint4* rows = (const uint4*)tbl;      // one row = 16 uint4 (256 B)

    const uint4 ec = rows[(size_t)c * 16 + li];
    const uint4 eo = rows[(size_t)o * 16 + li];

    float pd = dot_bf16x8(ec, eo);

    float nd[KK];
    #pragma unroll
    for (int k = 0; k < KK; ++k) {
        const int n = neg[b * KK + k];
        const uint4 en = rows[(size_t)n * 16 + li];
        nd[k] = dot_bf16x8(ec, en);
    }

    #pragma unroll
    for (int s = 1; s < 16; s <<= 1) {
        pd += __shfl_xor(pd, s);
        #pragma unroll
        for (int k = 0; k < KK; ++k) nd[k] += __shfl_xor(nd[k], s);
    }

    float loss = softplus_f(-pd);
    #pragma unroll
    for (int k = 0; k < KK; ++k) loss += softplus_f(nd[k]);

    __shared__ float smem[BPB];
    if (li == 0) smem[grp] = loss;
    __syncthreads();
    if (tid == 0) {
        float s = 0.0f;
        #pragma unroll
        for (int g = 0; g < BPB; ++g) s += smem[g];
        partial[blockIdx.x] = s;
    }
}

// ---- fp32 fallback (round-2 kernel) -------------------------------------
__device__ __forceinline__ float dot8(const float4& a0, const float4& a1,
                                      const float4& b0, const float4& b1) {
    float s = a0.x * b0.x;
    s = fmaf(a0.y, b0.y, s); s = fmaf(a0.z, b0.z, s); s = fmaf(a0.w, b0.w, s);
    s = fmaf(a1.x, b1.x, s); s = fmaf(a1.y, b1.y, s);
    s = fmaf(a1.z, b1.z, s); s = fmaf(a1.w, b1.w, s);
    return s;
}

__global__ __launch_bounds__(BLOCK) void
w2v_loss_f32_kernel(const int* __restrict__ cw,
                    const int* __restrict__ ow,
                    const int* __restrict__ neg,
                    const float* __restrict__ emb,
                    float* __restrict__ partial) {
    const int tid = threadIdx.x;
    const int li  = tid & 15;
    const int grp = tid >> 4;
    const int b   = blockIdx.x * BPB + grp;

    const int c = cw[b];
    const int o = ow[b];
    const float4* ebase = (const float4*)emb;
    const size_t f4 = (size_t)li * 2;

    const float4 ec0 = ebase[(size_t)c * 32 + f4];
    const float4 ec1 = ebase[(size_t)c * 32 + f4 + 1];
    const float4 eo0 = ebase[(size_t)o * 32 + f4];
    const float4 eo1 = ebase[(size_t)o * 32 + f4 + 1];

    float pd = dot8(ec0, ec1, eo0, eo1);
    float nd[KK];
    #pragma unroll
    for (int k = 0; k < KK; ++k) {
        const int n = neg[b * KK + k];
        const float4 en0 = ebase[(size_t)n * 32 + f4];
        const float4 en1 = ebase[(size_t)n * 32 + f4 + 1];
        nd[k] = dot8(ec0, ec1, en0, en1);
    }
    #pragma unroll
    for (int s = 1; s < 16; s <<= 1) {
        pd += __shfl_xor(pd, s);
        #pragma unroll
        for (int k = 0; k < KK; ++k) nd[k] += __shfl_xor(nd[k], s);
    }
    float loss = softplus_f(-pd);
    #pragma unroll
    for (int k = 0; k < KK; ++k) loss += softplus_f(nd[k]);

    __shared__ float smem[BPB];
    if (li == 0) smem[grp] = loss;
    __syncthreads();
    if (tid == 0) {
        float s = 0.0f;
        #pragma unroll
        for (int g = 0; g < BPB; ++g) s += smem[g];
        partial[blockIdx.x] = s;
    }
}

__global__ __launch_bounds__(256) void
w2v_reduce_kernel(const float* __restrict__ partial, float* __restrict__ out) {
    __shared__ float smem[256];
    float s = 0.0f;
    for (int i = threadIdx.x; i < GRID; i += 256) s += partial[i];
    smem[threadIdx.x] = s;
    __syncthreads();
    for (int step = 128; step > 0; step >>= 1) {
        if (threadIdx.x < step) smem[threadIdx.x] += smem[threadIdx.x + step];
        __syncthreads();
    }
    if (threadIdx.x == 0) out[0] = smem[0] / (float)BB;
}

extern "C" void kernel_launch(void* const* d_in, const int* in_sizes, int n_in,
                              void* d_out, int out_size, void* d_ws, size_t ws_size,
                              hipStream_t stream) {
    const int*   cw  = (const int*)d_in[0];
    const int*   ow  = (const int*)d_in[1];
    const int*   neg = (const int*)d_in[2];
    const float* emb = (const float*)d_in[3];
    float* out     = (float*)d_out;
    float* partial = (float*)d_ws;

    if (ws_size >= TBL_OFF + TBL_BYTES) {
        uint32_t* tbl = (uint32_t*)((char*)d_ws + TBL_OFF);
        convert_kernel<<<2048, 256, 0, stream>>>(emb, tbl);
        w2v_loss_bf16_kernel<<<GRID, BLOCK, 0, stream>>>(cw, ow, neg, tbl, partial);
    } else {
        w2v_loss_f32_kernel<<<GRID, BLOCK, 0, stream>>>(cw, ow, neg, emb, partial);
    }
    w2v_reduce_kernel<<<1, 256, 0, stream>>>(partial, out);
}

// Round 4
// 32.923 us; speedup vs baseline: 4.2264x; 1.4967x over previous
//
#include <hip/hip_runtime.h>
#include <math.h>
#include <stdint.h>

// Problem constants (match reference)
#define BB 65536
#define KK 10
#define EE 128
#define VV 100000

constexpr int BLOCK = 256;
constexpr int BPB   = 32;            // 32 groups of 8 lanes per block
constexpr int GRID  = BB / BPB;      // 2048 blocks (fp8 path)

constexpr size_t TBL_OFF   = 32768;              // fp8 table offset in ws
constexpr size_t TBL_BYTES = (size_t)VV * EE;    // 12.8 MB fp8

__device__ __forceinline__ float softplus_f(float x) {
    float ax = fabsf(x);
    return fmaxf(x, 0.0f) + __logf(1.0f + __expf(-ax));
}

// ---- fp32 -> fp8 e4m3 (RNE, HW cvt) table conversion --------------------
__global__ __launch_bounds__(256) void
convert_fp8_kernel(const float* __restrict__ emb, uint4* __restrict__ tbl) {
    const int nq = VV * EE / 16;                 // 800K chunks of 16 elems
    const int stride = gridDim.x * blockDim.x;
    for (int q = blockIdx.x * blockDim.x + threadIdx.x; q < nq; q += stride) {
        const float4* src = (const float4*)emb + (size_t)q * 4;
        const float4 f0 = src[0], f1 = src[1], f2 = src[2], f3 = src[3];
        uint32_t w[4];
        {
            int v = 0;
            v = __builtin_amdgcn_cvt_pk_fp8_f32(f0.x, f0.y, v, false);
            v = __builtin_amdgcn_cvt_pk_fp8_f32(f0.z, f0.w, v, true);
            w[0] = (uint32_t)v;
            v = 0;
            v = __builtin_amdgcn_cvt_pk_fp8_f32(f1.x, f1.y, v, false);
            v = __builtin_amdgcn_cvt_pk_fp8_f32(f1.z, f1.w, v, true);
            w[1] = (uint32_t)v;
            v = 0;
            v = __builtin_amdgcn_cvt_pk_fp8_f32(f2.x, f2.y, v, false);
            v = __builtin_amdgcn_cvt_pk_fp8_f32(f2.z, f2.w, v, true);
            w[2] = (uint32_t)v;
            v = 0;
            v = __builtin_amdgcn_cvt_pk_fp8_f32(f3.x, f3.y, v, false);
            v = __builtin_amdgcn_cvt_pk_fp8_f32(f3.z, f3.w, v, true);
            w[3] = (uint32_t)v;
        }
        tbl[q] = make_uint4(w[0], w[1], w[2], w[3]);
    }
}

// ---- fp8 gather + loss ---------------------------------------------------
// Decode one lane's 16 fp8 (uint4) into f32[16].
__device__ __forceinline__ void decode16(const uint4& u, float* f) {
    const uint32_t a[4] = {u.x, u.y, u.z, u.w};
    #pragma unroll
    for (int i = 0; i < 4; ++i) {
        auto lo = __builtin_amdgcn_cvt_pk_f32_fp8((int)a[i], false);
        auto hi = __builtin_amdgcn_cvt_pk_f32_fp8((int)a[i], true);
        f[4 * i + 0] = lo[0];
        f[4 * i + 1] = lo[1];
        f[4 * i + 2] = hi[0];
        f[4 * i + 3] = hi[1];
    }
}

__device__ __forceinline__ float dotd16(const float* cf, const uint4& u) {
    const uint32_t a[4] = {u.x, u.y, u.z, u.w};
    float s = 0.0f;
    #pragma unroll
    for (int i = 0; i < 4; ++i) {
        auto lo = __builtin_amdgcn_cvt_pk_f32_fp8((int)a[i], false);
        auto hi = __builtin_amdgcn_cvt_pk_f32_fp8((int)a[i], true);
        s = fmaf(cf[4 * i + 0], lo[0], s);
        s = fmaf(cf[4 * i + 1], lo[1], s);
        s = fmaf(cf[4 * i + 2], hi[0], s);
        s = fmaf(cf[4 * i + 3], hi[1], s);
    }
    return s;
}

__global__ __launch_bounds__(BLOCK) void
w2v_loss_fp8_kernel(const int* __restrict__ cw,
                    const int* __restrict__ ow,
                    const int* __restrict__ neg,
                    const uint4* __restrict__ rows,   // one row = 8 uint4 (128 B)
                    float* __restrict__ partial) {
    const int tid = threadIdx.x;
    const int li  = tid & 7;               // lane-in-group (8-lane groups)
    const int grp = tid >> 3;              // 0..31
    const int b   = blockIdx.x * BPB + grp;

    const int c = cw[b];
    const int o = ow[b];

    const uint4 ec = rows[(size_t)c * 8 + li];
    float cf[16];
    decode16(ec, cf);

    const uint4 eo = rows[(size_t)o * 8 + li];
    float pd = dotd16(cf, eo);

    float nd[KK];
    #pragma unroll
    for (int k = 0; k < KK; ++k) {
        const int n = neg[b * KK + k];
        const uint4 en = rows[(size_t)n * 8 + li];
        nd[k] = dotd16(cf, en);
    }

    // Reduce across the 8-lane group: masks 1,2,4.
    #pragma unroll
    for (int s = 1; s < 8; s <<= 1) {
        pd += __shfl_xor(pd, s);
        #pragma unroll
        for (int k = 0; k < KK; ++k) nd[k] += __shfl_xor(nd[k], s);
    }

    float loss = softplus_f(-pd);
    #pragma unroll
    for (int k = 0; k < KK; ++k) loss += softplus_f(nd[k]);

    __shared__ float smem[BPB];
    if (li == 0) smem[grp] = loss;
    __syncthreads();
    if (tid == 0) {
        float s = 0.0f;
        #pragma unroll
        for (int g = 0; g < BPB; ++g) s += smem[g];
        partial[blockIdx.x] = s;
    }
}

// ---- fp32 fallback (round-2 kernel, 16-lane groups) ---------------------
__device__ __forceinline__ float dot8(const float4& a0, const float4& a1,
                                      const float4& b0, const float4& b1) {
    float s = a0.x * b0.x;
    s = fmaf(a0.y, b0.y, s); s = fmaf(a0.z, b0.z, s); s = fmaf(a0.w, b0.w, s);
    s = fmaf(a1.x, b1.x, s); s = fmaf(a1.y, b1.y, s);
    s = fmaf(a1.z, b1.z, s); s = fmaf(a1.w, b1.w, s);
    return s;
}

__global__ __launch_bounds__(BLOCK) void
w2v_loss_f32_kernel(const int* __restrict__ cw,
                    const int* __restrict__ ow,
                    const int* __restrict__ neg,
                    const float* __restrict__ emb,
                    float* __restrict__ partial) {
    const int tid = threadIdx.x;
    const int li  = tid & 15;
    const int grp = tid >> 4;
    const int b   = blockIdx.x * 16 + grp;

    const int c = cw[b];
    const int o = ow[b];
    const float4* ebase = (const float4*)emb;
    const size_t f4 = (size_t)li * 2;

    const float4 ec0 = ebase[(size_t)c * 32 + f4];
    const float4 ec1 = ebase[(size_t)c * 32 + f4 + 1];
    const float4 eo0 = ebase[(size_t)o * 32 + f4];
    const float4 eo1 = ebase[(size_t)o * 32 + f4 + 1];

    float pd = dot8(ec0, ec1, eo0, eo1);
    float nd[KK];
    #pragma unroll
    for (int k = 0; k < KK; ++k) {
        const int n = neg[b * KK + k];
        const float4 en0 = ebase[(size_t)n * 32 + f4];
        const float4 en1 = ebase[(size_t)n * 32 + f4 + 1];
        nd[k] = dot8(ec0, ec1, en0, en1);
    }
    #pragma unroll
    for (int s = 1; s < 16; s <<= 1) {
        pd += __shfl_xor(pd, s);
        #pragma unroll
        for (int k = 0; k < KK; ++k) nd[k] += __shfl_xor(nd[k], s);
    }
    float loss = softplus_f(-pd);
    #pragma unroll
    for (int k = 0; k < KK; ++k) loss += softplus_f(nd[k]);

    __shared__ float smem[16];
    if (li == 0) smem[grp] = loss;
    __syncthreads();
    if (tid == 0) {
        float s = 0.0f;
        #pragma unroll
        for (int g = 0; g < 16; ++g) s += smem[g];
        partial[blockIdx.x] = s;
    }
}

__global__ __launch_bounds__(256) void
w2v_reduce_kernel(const float* __restrict__ partial, int n, float* __restrict__ out) {
    __shared__ float smem[256];
    float s = 0.0f;
    for (int i = threadIdx.x; i < n; i += 256) s += partial[i];
    smem[threadIdx.x] = s;
    __syncthreads();
    for (int step = 128; step > 0; step >>= 1) {
        if (threadIdx.x < step) smem[threadIdx.x] += smem[threadIdx.x + step];
        __syncthreads();
    }
    if (threadIdx.x == 0) out[0] = smem[0] / (float)BB;
}

extern "C" void kernel_launch(void* const* d_in, const int* in_sizes, int n_in,
                              void* d_out, int out_size, void* d_ws, size_t ws_size,
                              hipStream_t stream) {
    const int*   cw  = (const int*)d_in[0];
    const int*   ow  = (const int*)d_in[1];
    const int*   neg = (const int*)d_in[2];
    const float* emb = (const float*)d_in[3];
    float* out     = (float*)d_out;
    float* partial = (float*)d_ws;

    if (ws_size >= TBL_OFF + TBL_BYTES) {
        uint4* tbl = (uint4*)((char*)d_ws + TBL_OFF);
        convert_fp8_kernel<<<2048, 256, 0, stream>>>(emb, tbl);
        w2v_loss_fp8_kernel<<<GRID, BLOCK, 0, stream>>>(cw, ow, neg, tbl, partial);
        w2v_reduce_kernel<<<1, 256, 0, stream>>>(partial, GRID, out);
    } else {
        w2v_loss_f32_kernel<<<BB / 16, BLOCK, 0, stream>>>(cw, ow, neg, emb, partial);
        w2v_reduce_kernel<<<1, 256, 0, stream>>>(partial, BB / 16, out);
    }
}